// Round 3
// baseline (715.707 us; speedup 1.0000x reference)
//
#include <hip/hip_runtime.h>
#include <hip/hip_bf16.h>

// RecursiveNet bf16-MFMA, round 3.
//  - stage0: gather(perm)+fp32->bf16 via swizzled LDS tile, direct pooled stores
//  - stages 1..9: "direct" kernel — B fragments straight from global (L1/L2-hit),
//    zero LDS, zero barriers, A=[W0|W1] resident in VGPRs
//  - stages 10..17 (Lin<=511): fused single-block kernel, LDS ping-pong
// Effective bias (depth channels are time-constant) precomputed in fp32.

typedef __bf16 v8bf __attribute__((ext_vector_type(8)));
typedef float v16f __attribute__((ext_vector_type(16)));

__device__ __forceinline__ ushort f2bf(float f) {
    __hip_bfloat16 h = __float2bfloat16(f);
    return *reinterpret_cast<ushort*>(&h);
}
__device__ __forceinline__ unsigned pack2(float lo, float hi) {
    return (unsigned)f2bf(lo) | ((unsigned)f2bf(hi) << 16);
}
__device__ __forceinline__ float leaky(float y) { return (y >= 0.f) ? y : 0.2f * y; }

#define ZACC {0.f,0.f,0.f,0.f,0.f,0.f,0.f,0.f,0.f,0.f,0.f,0.f,0.f,0.f,0.f,0.f}

// ---------------------------------------------------------------------------
__global__ void bias_kernel(const float* __restrict__ W, const float* __restrict__ b,
                            const float* __restrict__ depth, float* __restrict__ Bst) {
    int i = blockIdx.x, o = threadIdx.x;
    const float* Wo = W + (size_t)o * 512 + 256;
    const float* di = depth + (size_t)i * 128;
    float s = b[o];
#pragma unroll 8
    for (int c = 0; c < 128; ++c) s += di[c] * (Wo[2 * c] + Wo[2 * c + 1]);
    Bst[i * 128 + o] = s;
}

__global__ void repack_kernel(const float* __restrict__ W, ushort* __restrict__ A) {
    int o = blockIdx.x, c = threadIdx.x;
    float v = (c < 128) ? W[(size_t)o * 512 + 2 * c] : W[(size_t)o * 512 + 2 * (c - 128) + 1];
    A[o * 256 + c] = f2bf(v);
}

// ---------------------------------------------------------------------------
// Common per-wave fragment setup
#define WAVE_SETUP()                                                          \
    const int tid = threadIdx.x;                                              \
    const int lane = tid & 63;                                                \
    const int w = tid >> 6;                                                   \
    const int n31 = lane & 31;                                                \
    const int h = lane >> 5;                                                  \
    v8bf af[16];                                                              \
    {                                                                         \
        const ushort* Arow = A + (size_t)(w * 32 + n31) * 256 + h * 8;        \
        _Pragma("unroll")                                                     \
        for (int s = 0; s < 16; ++s) af[s] = *(const v8bf*)&Arow[s * 16];     \
    }

#define LOAD_BIAS(Bs)                                                         \
    float bias_r[16];                                                         \
    _Pragma("unroll")                                                         \
    for (int r = 0; r < 16; ++r)                                              \
        bias_r[r] = (Bs)[w * 32 + (r & 3) + 8 * (r >> 2) + 4 * h];

// Epilogue: bias+leaky+pool(shfl) and store pooled row u (guarded).
// Dst is bf16 [Lp][128]; 8B chunk at channel w*32+8q+4h.
#define EPILOGUE_STORE_GLOBAL(acc, u, Lp, Y)                                  \
    {                                                                         \
        const bool act_ = !(lane & 1) && ((u) < (Lp));                        \
        _Pragma("unroll")                                                     \
        for (int q = 0; q < 4; ++q) {                                         \
            float p_[4];                                                      \
            _Pragma("unroll")                                                 \
            for (int j = 0; j < 4; ++j) {                                     \
                float y = leaky((acc)[4 * q + j] + bias_r[4 * q + j]);        \
                float y2 = __shfl_xor(y, 1, 64);                              \
                p_[j] = fmaxf(y, y2);                                         \
            }                                                                 \
            if (act_) {                                                       \
                uint2 v_;                                                     \
                v_.x = pack2(p_[0], p_[1]);                                   \
                v_.y = pack2(p_[2], p_[3]);                                   \
                *(uint2*)&(Y)[(size_t)(u) * 128 + w * 32 + 8 * q + 4 * h] = v_; \
            }                                                                 \
        }                                                                     \
    }

// ---------------------------------------------------------------------------
// Stage 0: fp32 gathered input -> LDS (bf16, 16B-chunk XOR swizzle) -> MFMA
__global__ __launch_bounds__(256)
void stage0_kernel(const float* __restrict__ x0, const int* __restrict__ perm,
                   const ushort* __restrict__ A, const float* __restrict__ Bst,
                   ushort* __restrict__ Y, int Lin, int Lp) {
    __shared__ __align__(16) ushort xs[129 * 128];
    __shared__ int prow[129];

    const int u0 = blockIdx.x * 64;
    const int t0 = u0 * 2;

    for (int r = threadIdx.x; r < 129; r += 256) {
        int t = t0 + r;
        prow[r] = (t < Lin) ? perm[t] : 0;
    }
    __syncthreads();
    for (int idx = threadIdx.x; idx < 129 * 16; idx += 256) {
        int row = idx >> 4, ck = idx & 15;
        int dst = row * 128 + ((ck ^ (row & 15)) * 8);
        if (t0 + row < Lin) {
            const float* s = x0 + (size_t)prow[row] * 128 + ck * 8;
            float4 a = *(const float4*)s;
            float4 bq = *(const float4*)(s + 4);
            uint4 v;
            v.x = pack2(a.x, a.y);  v.y = pack2(a.z, a.w);
            v.z = pack2(bq.x, bq.y); v.w = pack2(bq.z, bq.w);
            *(uint4*)&xs[dst] = v;
        } else {
            uint4 z = {0u, 0u, 0u, 0u};
            *(uint4*)&xs[dst] = z;
        }
    }
    __syncthreads();

    WAVE_SETUP();
    LOAD_BIAS(Bst);

#pragma unroll
    for (int nt = 0; nt < 4; ++nt) {
        const int row0 = nt * 32 + n31;
        const ushort* xr0 = &xs[row0 * 128];
        const ushort* xr1 = &xs[(row0 + 1) * 128];
        const int m0 = row0 & 15, m1 = (row0 + 1) & 15;
        v16f acc = ZACC;
#pragma unroll
        for (int s = 0; s < 8; ++s)
            acc = __builtin_amdgcn_mfma_f32_32x32x16_bf16(
                af[s], *(const v8bf*)&xr0[((2 * s + h) ^ m0) * 8], acc, 0, 0, 0);
#pragma unroll
        for (int s = 0; s < 8; ++s)
            acc = __builtin_amdgcn_mfma_f32_32x32x16_bf16(
                af[8 + s], *(const v8bf*)&xr1[((2 * s + h) ^ m1) * 8], acc, 0, 0, 0);
        const int u = u0 + nt * 16 + (n31 >> 1);
        EPILOGUE_STORE_GLOBAL(acc, u, Lp, Y);
    }
}

// ---------------------------------------------------------------------------
// Stages 1..9: B fragments direct from global (bf16 [Lin][128]); no LDS/barriers.
__global__ __launch_bounds__(256)
void stage_direct(const ushort* __restrict__ Xin, const ushort* __restrict__ A,
                  const float* __restrict__ Bst, ushort* __restrict__ Y,
                  int Lin, int Lp) {
    WAVE_SETUP();
    LOAD_BIAS(Bst);
    const int tb = blockIdx.x * 64;
#pragma unroll
    for (int nt = 0; nt < 2; ++nt) {
        const int t = tb + nt * 32 + n31;
        const int r0 = min(t, Lin - 1), r1 = min(t + 1, Lin - 1);
        const ushort* p0 = Xin + (size_t)r0 * 128 + h * 8;
        const ushort* p1 = Xin + (size_t)r1 * 128 + h * 8;
        v16f acc = ZACC;
#pragma unroll
        for (int s = 0; s < 8; ++s)
            acc = __builtin_amdgcn_mfma_f32_32x32x16_bf16(
                af[s], *(const v8bf*)&p0[s * 16], acc, 0, 0, 0);
#pragma unroll
        for (int s = 0; s < 8; ++s)
            acc = __builtin_amdgcn_mfma_f32_32x32x16_bf16(
                af[8 + s], *(const v8bf*)&p1[s * 16], acc, 0, 0, 0);
        const int u = t >> 1;
        EPILOGUE_STORE_GLOBAL(acc, u, Lp, Y);
    }
}

// ---------------------------------------------------------------------------
// Stages 10..17 fused (Lin = 511 -> 1), one block, LDS ping-pong.
__global__ __launch_bounds__(256)
void tail_fused(const ushort* __restrict__ Xg, const ushort* __restrict__ A,
                const float* __restrict__ BstAll, float* __restrict__ out) {
    extern __shared__ __align__(16) ushort tbuf[];
    ushort* buf0 = tbuf;              // 255 rows
    ushort* buf1 = tbuf + 255 * 128;  // 127 rows

    WAVE_SETUP();

    int Lin = 511;
    for (int st = 0; st < 8; ++st) {
        const int Lp = (Lin - 1) >> 1;
        LOAD_BIAS(BstAll + (size_t)(10 + st) * 128);
        ushort* dst = (st & 1) ? buf1 : buf0;
        const ushort* src = (st & 1) ? buf0 : buf1;  // unused for st==0
        const int ntiles = (Lin - 1 + 31) >> 5;
        for (int ti = 0; ti < ntiles; ++ti) {
            const int t = ti * 32 + n31;
            const int r0 = min(t, Lin - 1), r1 = min(t + 1, Lin - 1);
            v16f acc = ZACC;
            if (st == 0) {
                const ushort* p0 = Xg + (size_t)r0 * 128 + h * 8;
                const ushort* p1 = Xg + (size_t)r1 * 128 + h * 8;
#pragma unroll
                for (int s = 0; s < 8; ++s)
                    acc = __builtin_amdgcn_mfma_f32_32x32x16_bf16(
                        af[s], *(const v8bf*)&p0[s * 16], acc, 0, 0, 0);
#pragma unroll
                for (int s = 0; s < 8; ++s)
                    acc = __builtin_amdgcn_mfma_f32_32x32x16_bf16(
                        af[8 + s], *(const v8bf*)&p1[s * 16], acc, 0, 0, 0);
            } else {
                const ushort* sr0 = src + r0 * 128;
                const ushort* sr1 = src + r1 * 128;
                const int m0 = r0 & 15, m1 = r1 & 15;
#pragma unroll
                for (int s = 0; s < 8; ++s)
                    acc = __builtin_amdgcn_mfma_f32_32x32x16_bf16(
                        af[s], *(const v8bf*)&sr0[((2 * s + h) ^ m0) * 8], acc, 0, 0, 0);
#pragma unroll
                for (int s = 0; s < 8; ++s)
                    acc = __builtin_amdgcn_mfma_f32_32x32x16_bf16(
                        af[8 + s], *(const v8bf*)&sr1[((2 * s + h) ^ m1) * 8], acc, 0, 0, 0);
            }
            const int u = t >> 1;
            const bool act = !(lane & 1) && (u < Lp);
#pragma unroll
            for (int q = 0; q < 4; ++q) {
                float p[4];
#pragma unroll
                for (int j = 0; j < 4; ++j) {
                    float y = leaky(acc[4 * q + j] + bias_r[4 * q + j]);
                    float y2 = __shfl_xor(y, 1, 64);
                    p[j] = fmaxf(y, y2);
                }
                if (act) {
                    if (st < 7) {
                        const int c8 = 4 * w + q;
                        uint2 v;
                        v.x = pack2(p[0], p[1]);
                        v.y = pack2(p[2], p[3]);
                        *(uint2*)&dst[u * 128 + ((c8 ^ (u & 15)) * 8) + 4 * h] = v;
                    } else {
                        float4 o = {p[0], p[1], p[2], p[3]};
                        *(float4*)&out[w * 32 + 8 * q + 4 * h] = o;
                    }
                }
            }
        }
        __syncthreads();
        Lin = Lp;
    }
}

// ---------------------------------------------------------------------------
extern "C" void kernel_launch(void* const* d_in, const int* in_sizes, int n_in,
                              void* d_out, int out_size, void* d_ws, size_t ws_size,
                              hipStream_t stream) {
    const float* x     = (const float*)d_in[0];   // [524288][128]
    const float* depth = (const float*)d_in[1];   // [32][128]
    const float* W     = (const float*)d_in[2];   // [128][256][2]
    const float* b     = (const float*)d_in[3];   // [128]
    const int*   perm  = (const int*)d_in[4];     // [524288]
    float* out = (float*)d_out;                   // [1][128] fp32

    char* ws = (char*)d_ws;
    float*  Bst = (float*)ws;                                            // 18*128 fp32
    ushort* A   = (ushort*)(ws + 16384);                                 // 128*256 bf16
    ushort* R0  = (ushort*)(ws + 16384 + 65536);                         // 262143 rows
    ushort* R1  = (ushort*)(ws + 16384 + 65536 + (size_t)262143 * 256);  // 131071 rows

    bias_kernel<<<18, 128, 0, stream>>>(W, b, depth, Bst);
    repack_kernel<<<128, 256, 0, stream>>>(W, A);

    // stage 0: 524288 -> 262143
    stage0_kernel<<<4096, 256, 0, stream>>>(x, perm, A, Bst, R0, 524288, 262143);

    // stages 1..9: 262143 -> 511
    int Lin = 262143;
    const ushort* in = R0;
    for (int i = 1; i <= 9; ++i) {
        int Lp = (Lin - 1) >> 1;
        ushort* outb = (i & 1) ? R1 : R0;
        int blocks = (Lin - 1 + 63) / 64;
        stage_direct<<<blocks, 256, 0, stream>>>(in, A, Bst + (size_t)i * 128,
                                                 outb, Lin, Lp);
        in = outb;
        Lin = Lp;
    }

    // stages 10..17 fused: 511 -> 1 (in == R1 here)
    tail_fused<<<1, 256, (255 + 127) * 128 * 2, stream>>>(in, A, Bst, out);
}

// Round 4
// 555.927 us; speedup vs baseline: 1.2874x; 1.2874x over previous
//
#include <hip/hip_runtime.h>
#include <hip/hip_bf16.h>

// RecursiveNet bf16-MFMA, round 4: stage-PAIR fusion.
//   pair_fused(i,i+1): block -> 32 outputs of stage i+1; stage-i intermediate
//   (65 rows) lives only in LDS. Stages (0,1),(2,3),(4,5),(6,7),(8,9), then
//   tail_fused handles 10..17 (Lin=511 -> 1) in one block.
// A=[W0|W1] (128x256 bf16) resident in VGPRs per wave; effective bias fp32.

typedef __bf16 v8bf __attribute__((ext_vector_type(8)));
typedef float v16f __attribute__((ext_vector_type(16)));

__device__ __forceinline__ ushort f2bf(float f) {
    __hip_bfloat16 h = __float2bfloat16(f);
    return *reinterpret_cast<ushort*>(&h);
}
__device__ __forceinline__ unsigned pack2(float lo, float hi) {
    return (unsigned)f2bf(lo) | ((unsigned)f2bf(hi) << 16);
}
__device__ __forceinline__ float leaky(float y) { return (y >= 0.f) ? y : 0.2f * y; }

#define ZACC {0.f,0.f,0.f,0.f,0.f,0.f,0.f,0.f,0.f,0.f,0.f,0.f,0.f,0.f,0.f,0.f}

// ---------------------------------------------------------------------------
__global__ void bias_kernel(const float* __restrict__ W, const float* __restrict__ b,
                            const float* __restrict__ depth, float* __restrict__ Bst) {
    int i = blockIdx.x, o = threadIdx.x;
    const float* Wo = W + (size_t)o * 512 + 256;
    const float* di = depth + (size_t)i * 128;
    float s = b[o];
#pragma unroll 8
    for (int c = 0; c < 128; ++c) s += di[c] * (Wo[2 * c] + Wo[2 * c + 1]);
    Bst[i * 128 + o] = s;
}

__global__ void repack_kernel(const float* __restrict__ W, ushort* __restrict__ A) {
    int o = blockIdx.x, c = threadIdx.x;
    float v = (c < 128) ? W[(size_t)o * 512 + 2 * c] : W[(size_t)o * 512 + 2 * (c - 128) + 1];
    A[o * 256 + c] = f2bf(v);
}

// ---------------------------------------------------------------------------
#define WAVE_SETUP()                                                          \
    const int tid = threadIdx.x;                                              \
    const int lane = tid & 63;                                                \
    const int w = tid >> 6;                                                   \
    const int n31 = lane & 31;                                                \
    const int h = lane >> 5;                                                  \
    v8bf af[16];                                                              \
    {                                                                         \
        const ushort* Arow = A + (size_t)(w * 32 + n31) * 256 + h * 8;        \
        _Pragma("unroll")                                                     \
        for (int s = 0; s < 16; ++s) af[s] = *(const v8bf*)&Arow[s * 16];     \
    }

#define LOAD_BIAS(dst_, Bs)                                                   \
    float dst_[16];                                                           \
    _Pragma("unroll")                                                         \
    for (int r = 0; r < 16; ++r)                                              \
        dst_[r] = (Bs)[w * 32 + (r & 3) + 8 * (r >> 2) + 4 * h];

// 16 MFMA from a swizzled LDS tile (rows r0_, r1_ local, pre-clamped)
#define MFMA_TILE_LDS(buf, r0_, r1_, acc)                                     \
    {                                                                         \
        const ushort* sp0 = (buf) + (r0_) * 128;                              \
        const ushort* sp1 = (buf) + (r1_) * 128;                              \
        const int mm0 = (r0_) & 15, mm1 = (r1_) & 15;                         \
        _Pragma("unroll")                                                     \
        for (int s = 0; s < 8; ++s)                                           \
            acc = __builtin_amdgcn_mfma_f32_32x32x16_bf16(                    \
                af[s], *(const v8bf*)&sp0[((2 * s + h) ^ mm0) * 8], acc, 0, 0, 0); \
        _Pragma("unroll")                                                     \
        for (int s = 0; s < 8; ++s)                                           \
            acc = __builtin_amdgcn_mfma_f32_32x32x16_bf16(                    \
                af[8 + s], *(const v8bf*)&sp1[((2 * s + h) ^ mm1) * 8], acc, 0, 0, 0); \
    }

// ---------------------------------------------------------------------------
// Fused pair of stages. Block -> 32 outputs of the second stage.
//   input rows needed : [4U, 4U+131]  (132 staged, clamped)
//   stage-A convs     : local p in [0,130)  -> 5 tiles (tail garbage guarded)
//   stage-A pooled    : 65 rows in LDS (bf16, swizzled)
//   stage-B convs     : local p in [0,64)   -> 2 tiles -> global store
__global__ __launch_bounds__(256)
void pair_fused(const ushort* __restrict__ Xin,   // bf16 [Lin][128] (stage>0)
                const float* __restrict__ x0,     // fp32 [N][128]  (first pair)
                const int* __restrict__ perm,     // [N]            (first pair)
                const ushort* __restrict__ A,     // bf16 [128][256]
                const float* __restrict__ Bst2,   // fp32 [2][128]
                ushort* __restrict__ Y,           // bf16 [Lp2][128]
                int Lin, int Lp2, int stage0) {
    __shared__ __align__(16) ushort xin[132 * 128];  // 33 KB
    __shared__ __align__(16) ushort mid[65 * 128];   // 16.6 KB
    __shared__ int prow[132];

    const int U = blockIdx.x * 32;
    const int t0 = U * 4;

    if (stage0) {
        for (int r = threadIdx.x; r < 132; r += 256)
            prow[r] = perm[min(t0 + r, Lin - 1)];
        __syncthreads();
    }
    for (int idx = threadIdx.x; idx < 132 * 16; idx += 256) {
        int row = idx >> 4, ck = idx & 15;
        int t = min(t0 + row, Lin - 1);
        int dst = row * 128 + ((ck ^ (row & 15)) * 8);
        if (stage0) {
            const float* s = x0 + (size_t)prow[row] * 128 + ck * 8;
            float4 a = *(const float4*)s;
            float4 bq = *(const float4*)(s + 4);
            uint4 v;
            v.x = pack2(a.x, a.y);  v.y = pack2(a.z, a.w);
            v.z = pack2(bq.x, bq.y); v.w = pack2(bq.z, bq.w);
            *(uint4*)&xin[dst] = v;
        } else {
            *(uint4*)&xin[dst] = *(const uint4*)&Xin[(size_t)t * 128 + ck * 8];
        }
    }
    __syncthreads();

    WAVE_SETUP();

    // ---- stage A: 5 tiles -> mid (LDS)
    {
        LOAD_BIAS(bias_r, Bst2);
#pragma unroll
        for (int ti = 0; ti < 5; ++ti) {
            const int p = 32 * ti + n31;
            const int r0 = min(p, 131), r1 = min(p + 1, 131);
            v16f acc = ZACC;
            MFMA_TILE_LDS(xin, r0, r1, acc);
            const int u1 = 16 * ti + (n31 >> 1);
            const bool act = !(lane & 1) && (u1 < 65);
#pragma unroll
            for (int q = 0; q < 4; ++q) {
                float pv[4];
#pragma unroll
                for (int j = 0; j < 4; ++j) {
                    float y = leaky(acc[4 * q + j] + bias_r[4 * q + j]);
                    float y2 = __shfl_xor(y, 1, 64);
                    pv[j] = fmaxf(y, y2);
                }
                if (act) {
                    uint2 v;
                    v.x = pack2(pv[0], pv[1]);
                    v.y = pack2(pv[2], pv[3]);
                    *(uint2*)&mid[u1 * 128 + (((4 * w + q) ^ (u1 & 15)) * 8) + 4 * h] = v;
                }
            }
        }
    }
    __syncthreads();

    // ---- stage B: 2 tiles -> global
    {
        LOAD_BIAS(bias_r, Bst2 + 128);
#pragma unroll
        for (int ti = 0; ti < 2; ++ti) {
            const int p = 32 * ti + n31;
            v16f acc = ZACC;
            MFMA_TILE_LDS(mid, p, p + 1, acc);
            const int u2 = U + 16 * ti + (n31 >> 1);
            const bool act = !(lane & 1) && (u2 < Lp2);
#pragma unroll
            for (int q = 0; q < 4; ++q) {
                float pv[4];
#pragma unroll
                for (int j = 0; j < 4; ++j) {
                    float y = leaky(acc[4 * q + j] + bias_r[4 * q + j]);
                    float y2 = __shfl_xor(y, 1, 64);
                    pv[j] = fmaxf(y, y2);
                }
                if (act) {
                    uint2 v;
                    v.x = pack2(pv[0], pv[1]);
                    v.y = pack2(pv[2], pv[3]);
                    *(uint2*)&Y[(size_t)u2 * 128 + w * 32 + 8 * q + 4 * h] = v;
                }
            }
        }
    }
}

// ---------------------------------------------------------------------------
// Stages 10..17 fused (Lin = 511 -> 1), one block, LDS ping-pong.
__global__ __launch_bounds__(256)
void tail_fused(const ushort* __restrict__ Xg, const ushort* __restrict__ A,
                const float* __restrict__ BstAll, float* __restrict__ out) {
    extern __shared__ __align__(16) ushort tbuf[];
    ushort* buf0 = tbuf;              // 255 rows
    ushort* buf1 = tbuf + 255 * 128;  // 127 rows

    WAVE_SETUP();

    int Lin = 511;
    for (int st = 0; st < 8; ++st) {
        const int Lp = (Lin - 1) >> 1;
        LOAD_BIAS(bias_r, BstAll + (size_t)(10 + st) * 128);
        ushort* dst = (st & 1) ? buf1 : buf0;
        const ushort* src = (st & 1) ? buf0 : buf1;  // unused for st==0
        const int ntiles = (Lin - 1 + 31) >> 5;
        for (int ti = 0; ti < ntiles; ++ti) {
            const int t = ti * 32 + n31;
            const int r0 = min(t, Lin - 1), r1 = min(t + 1, Lin - 1);
            v16f acc = ZACC;
            if (st == 0) {
                const ushort* p0 = Xg + (size_t)r0 * 128 + h * 8;
                const ushort* p1 = Xg + (size_t)r1 * 128 + h * 8;
#pragma unroll
                for (int s = 0; s < 8; ++s)
                    acc = __builtin_amdgcn_mfma_f32_32x32x16_bf16(
                        af[s], *(const v8bf*)&p0[s * 16], acc, 0, 0, 0);
#pragma unroll
                for (int s = 0; s < 8; ++s)
                    acc = __builtin_amdgcn_mfma_f32_32x32x16_bf16(
                        af[8 + s], *(const v8bf*)&p1[s * 16], acc, 0, 0, 0);
            } else {
                MFMA_TILE_LDS(src, r0, r1, acc);
            }
            const int u = t >> 1;
            const bool act = !(lane & 1) && (u < Lp);
#pragma unroll
            for (int q = 0; q < 4; ++q) {
                float pv[4];
#pragma unroll
                for (int j = 0; j < 4; ++j) {
                    float y = leaky(acc[4 * q + j] + bias_r[4 * q + j]);
                    float y2 = __shfl_xor(y, 1, 64);
                    pv[j] = fmaxf(y, y2);
                }
                if (act) {
                    if (st < 7) {
                        uint2 v;
                        v.x = pack2(pv[0], pv[1]);
                        v.y = pack2(pv[2], pv[3]);
                        *(uint2*)&dst[u * 128 + (((4 * w + q) ^ (u & 15)) * 8) + 4 * h] = v;
                    } else {
                        float4 o = {pv[0], pv[1], pv[2], pv[3]};
                        *(float4*)&out[w * 32 + 8 * q + 4 * h] = o;
                    }
                }
            }
        }
        __syncthreads();
        Lin = Lp;
    }
}

// ---------------------------------------------------------------------------
extern "C" void kernel_launch(void* const* d_in, const int* in_sizes, int n_in,
                              void* d_out, int out_size, void* d_ws, size_t ws_size,
                              hipStream_t stream) {
    const float* x     = (const float*)d_in[0];   // [524288][128]
    const float* depth = (const float*)d_in[1];   // [32][128]
    const float* W     = (const float*)d_in[2];   // [128][256][2]
    const float* b     = (const float*)d_in[3];   // [128]
    const int*   perm  = (const int*)d_in[4];     // [524288]
    float* out = (float*)d_out;                   // [1][128] fp32

    char* ws = (char*)d_ws;
    float*  Bst = (float*)ws;                                            // 18*128 fp32
    ushort* A   = (ushort*)(ws + 16384);                                 // 128*256 bf16
    ushort* R0  = (ushort*)(ws + 16384 + 65536);                         // 131071 rows max
    ushort* R1  = (ushort*)(ws + 16384 + 65536 + (size_t)131071 * 256);  // 32767 rows max

    bias_kernel<<<18, 128, 0, stream>>>(W, b, depth, Bst);
    repack_kernel<<<128, 256, 0, stream>>>(W, A);

    // (0,1): 524288 -> 131071
    pair_fused<<<4096, 256, 0, stream>>>(nullptr, x, perm, A, Bst, R0,
                                         524288, 131071, 1);
    // (2,3): 131071 -> 32767
    pair_fused<<<1024, 256, 0, stream>>>(R0, nullptr, nullptr, A, Bst + 2 * 128, R1,
                                         131071, 32767, 0);
    // (4,5): 32767 -> 8191
    pair_fused<<<256, 256, 0, stream>>>(R1, nullptr, nullptr, A, Bst + 4 * 128, R0,
                                        32767, 8191, 0);
    // (6,7): 8191 -> 2047
    pair_fused<<<64, 256, 0, stream>>>(R0, nullptr, nullptr, A, Bst + 6 * 128, R1,
                                       8191, 2047, 0);
    // (8,9): 2047 -> 511
    pair_fused<<<16, 256, 0, stream>>>(R1, nullptr, nullptr, A, Bst + 8 * 128, R0,
                                       2047, 511, 0);
    // 10..17: 511 -> 1
    tail_fused<<<1, 256, (255 + 127) * 128 * 2, stream>>>(R0, A, Bst, out);
}